// Round 2
// baseline (194.973 us; speedup 1.0000x reference)
//
#include <hip/hip_runtime.h>
#include <hip/hip_bf16.h>

// GAT layer on MI355X. Round 17: delete the k_fine stage. Round-16 profile:
// all of our kernels < 42 us (top-5 = 256 MiB 0xAA workspace poison fills at
// 80% HBM peak = fixed ~42 us floor in the timed region); wall = serialized
// pipeline sum. So: remove a whole stage instead of shaving one.
// (1) Edge path scatters DIRECTLY into per-node fixed-stride slots
//     (eidx[dst*96 + atomicAdd(deg[dst])] = src). Poisson(16) max degree
//     ~40 << 96. No LDS histogram/scan, no pairs buffer, no k_fine.
// (2) exp(leaky_relu(el+er)) + denominator computed INLINE in the gather
//     loop of k_agg (el = 200 KB, L2-resident parallel gather).
// (3) k_mega: no LDS at all now; __launch_bounds__(256,4) (cap 128 VGPR,
//     no spill risk) -> 4 blk/CU resource cap.
// 3 dispatches. I/O: fp32 in, int32 idx, fp32 out.

#define NNODES 50000
#define NEDGES 800000
#define IN_F   256
#define HID    128
#define OUTF   64

#define EDEG   96                                        // per-node slot stride
#define EB     224                                       // edge-scatter blocks
#define NSTRIP (NNODES / 16)                             // 3125 strips
#define GB     ((NSTRIP + 3) / 4)                        // 782 gemm blocks

typedef unsigned short u16;
typedef unsigned long long u64;
typedef __bf16 bf16x8 __attribute__((ext_vector_type(8)));
typedef float  f32x4  __attribute__((ext_vector_type(4)));

__device__ __forceinline__ u16 f2b(float f) {
    union { float f; unsigned u; } v; v.f = f;
    unsigned u = v.u;
    return (u16)((u + 0x7fffu + ((u >> 16) & 1u)) >> 16);  // RNE fp32->bf16
}
__device__ __forceinline__ float b2f_lo(unsigned v) {
    union { unsigned u; float f; } c; c.u = (v & 0xffffu) << 16; return c.f;
}
__device__ __forceinline__ float b2f_hi(unsigned v) {
    union { unsigned u; float f; } c; c.u = v & 0xffff0000u; return c.f;
}
__device__ __forceinline__ float lrelu02_exp(float t) {
    t = t > 0.f ? t : 0.2f * t;                        // leaky_relu(0.2)
    return __expf(t);
}

// ---------------------------------------------------------------------------
// pack0: blocks 0..15 pack W_gat, 16..19 pack W_lin, 20.. zero deg[50000].
__global__ __launch_bounds__(256) void pack0(const float* __restrict__ Wg,
                                             const float* __restrict__ Wl,
                                             u16* __restrict__ pWg,
                                             u16* __restrict__ pWl,
                                             int* __restrict__ deg) {
    int blk = blockIdx.x, tid = threadIdx.x;
    if (blk < 16) {
        int t = blk * 256 + tid;
        int lane = t & 63, tile = t >> 6;
        int nt = tile & 7, kt = tile >> 3;
        int col = lane & 15, quad = lane >> 4;
        int krow = kt * 32 + quad * 8;
        int ncol = nt * 16 + col;
#pragma unroll
        for (int j = 0; j < 8; j++) pWg[t * 8 + j] = f2b(Wg[(krow + j) * HID + ncol]);
    } else if (blk < 20) {
        int t = (blk - 16) * 256 + tid;
        int lane = t & 63, tile = t >> 6;
        int nt = tile & 3, kt = tile >> 2;
        int col = lane & 15, quad = lane >> 4;
        int o  = nt * 16 + col;
        int k0 = kt * 32 + quad * 8;
#pragma unroll
        for (int j = 0; j < 8; j++) pWl[t * 8 + j] = f2b(Wl[o * HID + k0 + j]);
    } else {
        int t = (blk - 20) * 256 + tid;
        if (t < NNODES) deg[t] = 0;
    }
}

// ---------------------------------------------------------------------------
// k_mega: blocks [0,GB) = feat GEMM (1 strip/wave, fused el/er epilogue);
// blocks [GB, GB+EB) = edge scatter into per-node slot regions.
// The two paths are data-independent and run concurrently. No LDS.
__global__ __launch_bounds__(256, 4) void k_mega(
        const float* __restrict__ x, const u16* __restrict__ pWg,
        const float* __restrict__ al_, const float* __restrict__ ar_,
        unsigned* __restrict__ feat2, float* __restrict__ el, float* __restrict__ er,
        const int* __restrict__ src, const int* __restrict__ dst,
        int* __restrict__ deg, int* __restrict__ eidx) {
    int blk = blockIdx.x, tid = threadIdx.x;

    if (blk < GB) {
        // ---- feat GEMM path ----
        int wave = tid >> 6, lane = tid & 63;
        int strip = blk * 4 + wave;
        if (strip >= NSTRIP) return;
        int m0 = strip * 16;
        int col = lane & 15, quad = lane >> 4;

        f32x4 acc[8] = {};
        const float* xr = x + (size_t)(m0 + col) * IN_F + quad * 8;
#pragma unroll
        for (int kt = 0; kt < 8; kt++) {
            f32x4 a0 = *reinterpret_cast<const f32x4*>(xr + kt * 32);
            f32x4 a1 = *reinterpret_cast<const f32x4*>(xr + kt * 32 + 4);
            bf16x8 av;
#pragma unroll
            for (int j = 0; j < 4; j++) {
                av[j] = (__bf16)a0[j]; av[4 + j] = (__bf16)a1[j];
            }
#pragma unroll
            for (int nt = 0; nt < 8; nt++) {
                bf16x8 b = *reinterpret_cast<const bf16x8*>(pWg + ((kt * 8 + nt) * 64 + lane) * 8);
                acc[nt] = __builtin_amdgcn_mfma_f32_16x16x32_bf16(av, b, acc[nt], 0, 0, 0);
            }
        }
        // epilogue: el/er dot products + bf16 feat store
        float pl[4] = {0, 0, 0, 0}, pr[4] = {0, 0, 0, 0};
#pragma unroll
        for (int nt = 0; nt < 8; nt++) {
            float alv = al_[nt * 16 + col], arv = ar_[nt * 16 + col];
#pragma unroll
            for (int reg = 0; reg < 4; reg++) {
                pl[reg] += acc[nt][reg] * alv;
                pr[reg] += acc[nt][reg] * arv;
            }
        }
#pragma unroll
        for (int m = 1; m < 16; m <<= 1)
#pragma unroll
            for (int reg = 0; reg < 4; reg++) {
                pl[reg] += __shfl_xor(pl[reg], m, 64);
                pr[reg] += __shfl_xor(pr[reg], m, 64);
            }
        if (col == 0) {
#pragma unroll
            for (int reg = 0; reg < 4; reg++) {
                el[m0 + quad * 4 + reg] = pl[reg];
                er[m0 + quad * 4 + reg] = pr[reg];
            }
        }
#pragma unroll
        for (int nt = 0; nt < 8; nt++)
#pragma unroll
            for (int reg = 0; reg < 4; reg++) {
                u16* fp = (u16*)feat2;
                fp[(size_t)(m0 + quad * 4 + reg) * HID + nt * 16 + col] = f2b(acc[nt][reg]);
            }
        return;
    }

    // ---- edge scatter path ----
    int e0 = (blk - GB) * 256 + tid;
    for (int e = e0; e < NEDGES; e += EB * 256) {
        int s = src[e], d = dst[e];
        int slot = atomicAdd(&deg[d], 1);
        eidx[(size_t)d * EDEG + slot] = s;
    }
}

// ---------------------------------------------------------------------------
// Fused attention-weight + aggregation + output GEMM. One wave per node
// (4 nodes/wave over the block's 16-node strip). Per edge: src from eidx,
// el[src] gather (L2-resident 200 KB), w = exp(lrelu02(el+er)) inline,
// accumulate w*feat2[src] and denominator; normalize, bias, lrelu(0.01),
// then 16x16 MFMA with packed W_lin.
__global__ __launch_bounds__(256) void k_agg(const int* __restrict__ deg,
                                             const int* __restrict__ eidx,
                                             const float* __restrict__ el,
                                             const float* __restrict__ er,
                                             const unsigned* __restrict__ feat2,
                                             const float* __restrict__ bias,
                                             const u16* __restrict__ pWl,
                                             float* __restrict__ out) {
    __shared__ unsigned sg[16 * 68];
    int wave = threadIdx.x >> 6, lane = threadIdx.x & 63;
    int m0 = blockIdx.x * 16;
    float bl = bias[lane * 2 + 0], bh = bias[lane * 2 + 1];

    for (int i = 0; i < 4; i++) {
        int r = wave * 4 + i;
        int n = m0 + r;
        int cnt = deg[n];
        const int* ep = eidx + (size_t)n * EDEG;
        float ern = er[n];

        float p0 = 0.f, p1 = 0.f, q0 = 0.f, q1 = 0.f;
        float r0 = 0.f, r1 = 0.f, t0 = 0.f, t1 = 0.f;
        float u0 = 0.f, u1 = 0.f, x0 = 0.f, x1 = 0.f;
        float y0 = 0.f, y1 = 0.f, z0 = 0.f, z1 = 0.f;
        float dn = 0.f;
        int j = 0;
        for (; j + 8 <= cnt; j += 8) {
            int4 sa = *reinterpret_cast<const int4*>(ep + j);
            int4 sb = *reinterpret_cast<const int4*>(ep + j + 4);
            float e0 = el[sa.x], e1 = el[sa.y], e2 = el[sa.z], e3 = el[sa.w];
            float e4 = el[sb.x], e5 = el[sb.y], e6 = el[sb.z], e7 = el[sb.w];
            unsigned v0 = feat2[(size_t)sa.x * 64 + lane];
            unsigned v1 = feat2[(size_t)sa.y * 64 + lane];
            unsigned v2 = feat2[(size_t)sa.z * 64 + lane];
            unsigned v3 = feat2[(size_t)sa.w * 64 + lane];
            unsigned v4 = feat2[(size_t)sb.x * 64 + lane];
            unsigned v5 = feat2[(size_t)sb.y * 64 + lane];
            unsigned v6 = feat2[(size_t)sb.z * 64 + lane];
            unsigned v7 = feat2[(size_t)sb.w * 64 + lane];
            float w0 = lrelu02_exp(e0 + ern), w1 = lrelu02_exp(e1 + ern);
            float w2 = lrelu02_exp(e2 + ern), w3 = lrelu02_exp(e3 + ern);
            float w4 = lrelu02_exp(e4 + ern), w5 = lrelu02_exp(e5 + ern);
            float w6 = lrelu02_exp(e6 + ern), w7 = lrelu02_exp(e7 + ern);
            p0 += w0 * b2f_lo(v0); p1 += w0 * b2f_hi(v0);
            q0 += w1 * b2f_lo(v1); q1 += w1 * b2f_hi(v1);
            r0 += w2 * b2f_lo(v2); r1 += w2 * b2f_hi(v2);
            t0 += w3 * b2f_lo(v3); t1 += w3 * b2f_hi(v3);
            u0 += w4 * b2f_lo(v4); u1 += w4 * b2f_hi(v4);
            x0 += w5 * b2f_lo(v5); x1 += w5 * b2f_hi(v5);
            y0 += w6 * b2f_lo(v6); y1 += w6 * b2f_hi(v6);
            z0 += w7 * b2f_lo(v7); z1 += w7 * b2f_hi(v7);
            dn += ((w0 + w1) + (w2 + w3)) + ((w4 + w5) + (w6 + w7));
        }
        if (j + 4 <= cnt) {
            int4 sa = *reinterpret_cast<const int4*>(ep + j);
            float e0 = el[sa.x], e1 = el[sa.y], e2 = el[sa.z], e3 = el[sa.w];
            unsigned v0 = feat2[(size_t)sa.x * 64 + lane];
            unsigned v1 = feat2[(size_t)sa.y * 64 + lane];
            unsigned v2 = feat2[(size_t)sa.z * 64 + lane];
            unsigned v3 = feat2[(size_t)sa.w * 64 + lane];
            float w0 = lrelu02_exp(e0 + ern), w1 = lrelu02_exp(e1 + ern);
            float w2 = lrelu02_exp(e2 + ern), w3 = lrelu02_exp(e3 + ern);
            p0 += w0 * b2f_lo(v0); p1 += w0 * b2f_hi(v0);
            q0 += w1 * b2f_lo(v1); q1 += w1 * b2f_hi(v1);
            r0 += w2 * b2f_lo(v2); r1 += w2 * b2f_hi(v2);
            t0 += w3 * b2f_lo(v3); t1 += w3 * b2f_hi(v3);
            dn += (w0 + w1) + (w2 + w3);
            j += 4;
        }
        for (; j < cnt; j++) {
            int s = ep[j];
            float w = lrelu02_exp(el[s] + ern);
            unsigned v = feat2[(size_t)s * 64 + lane];
            p0 += w * b2f_lo(v); p1 += w * b2f_hi(v);
            dn += w;
        }
        float a0 = ((p0 + q0) + (r0 + t0)) + ((u0 + x0) + (y0 + z0));
        float a1 = ((p1 + q1) + (r1 + t1)) + ((u1 + x1) + (y1 + z1));

        float inv = dn > 0.f ? 1.f / dn : 0.f;         // isolated node -> 0
        float g0 = a0 * inv + bl;
        float g1 = a1 * inv + bh;
        g0 = g0 > 0.f ? g0 : 0.01f * g0;               // leaky_relu(0.01)
        g1 = g1 > 0.f ? g1 : 0.01f * g1;
        sg[r * 68 + lane] = (unsigned)f2b(g0) | ((unsigned)f2b(g1) << 16);
    }
    __syncthreads();

    int col = lane & 15, quad = lane >> 4;
    int nt = wave;
    f32x4 acc = {};
#pragma unroll
    for (int kt = 0; kt < 4; kt++) {
        bf16x8 a = *reinterpret_cast<const bf16x8*>(&sg[col * 68 + kt * 16 + quad * 4]);
        bf16x8 bf = *reinterpret_cast<const bf16x8*>(pWl + ((kt * 4 + nt) * 64 + lane) * 8);
        acc = __builtin_amdgcn_mfma_f32_16x16x32_bf16(a, bf, acc, 0, 0, 0);
    }
#pragma unroll
    for (int reg = 0; reg < 4; reg++)
        out[(size_t)(m0 + quad * 4 + reg) * OUTF + nt * 16 + col] = acc[reg];
}

// ---------------------------------------------------------------------------
extern "C" void kernel_launch(void* const* d_in, const int* in_sizes, int n_in,
                              void* d_out, int out_size, void* d_ws, size_t ws_size,
                              hipStream_t stream) {
    const float* x      = (const float*)d_in[0];   // [50000,256] fp32
    const int*   src    = (const int*)d_in[1];     // [800000] int32
    const int*   dst    = (const int*)d_in[2];     // [800000] int32
    const float* Wg     = (const float*)d_in[3];   // [256,128] fp32
    const float* attn_l = (const float*)d_in[4];   // [128]
    const float* attn_r = (const float*)d_in[5];   // [128]
    const float* bias   = (const float*)d_in[6];   // [128]
    const float* Wl     = (const float*)d_in[7];   // [64,128] fp32
    float* out          = (float*)d_out;           // [50000,64] fp32

    char* ws = (char*)d_ws;
    size_t off = 0;
    auto alloc = [&](size_t b) { size_t r = off; off += (b + 255) & ~(size_t)255; return r; };
    size_t pwgOff  = alloc((size_t)8 * 8 * 64 * 8 * 2);     // 64 KB
    size_t pwlOff  = alloc((size_t)4 * 4 * 64 * 8 * 2);     // 16 KB
    size_t featOff = alloc((size_t)NNODES * HID * 2);       // 12.8 MB bf16 feat
    size_t elOff   = alloc((size_t)NNODES * 4);
    size_t erOff   = alloc((size_t)NNODES * 4);
    size_t eidxOff = alloc((size_t)NNODES * EDEG * 4);      // 19.2 MB slot regions
    size_t degOff  = alloc((size_t)NNODES * 4);

    u16*      pWg   = (u16*)(ws + pwgOff);
    u16*      pWl   = (u16*)(ws + pwlOff);
    unsigned* feat2 = (unsigned*)(ws + featOff);
    float*    el    = (float*)(ws + elOff);
    float*    er    = (float*)(ws + erOff);
    int*      eidx  = (int*)(ws + eidxOff);
    int*      deg   = (int*)(ws + degOff);

    pack0<<<20 + (NNODES + 255) / 256, 256, 0, stream>>>(Wg, Wl, pWg, pWl, deg);
    k_mega<<<GB + EB, 256, 0, stream>>>(x, pWg, attn_l, attn_r, feat2, el, er,
                                        src, dst, deg, eidx);
    k_agg<<<NNODES / 16, 256, 0, stream>>>(deg, eidx, el, er, feat2, bias,
                                           pWl, out);
}

// Round 3
// 174.630 us; speedup vs baseline: 1.1165x; 1.1165x over previous
//
#include <hip/hip_runtime.h>
#include <hip/hip_bf16.h>

// GAT layer on MI355X. Round 18: revert round-17's direct scatter (cross-XCD
// partial-line writeback amplified eidx writes 20->61 MB; deg atomics
// serialized; k_mega 65 us). Back to round-16 structure (LDS-bucketed
// partition + k_fine + k_aggout, wall 175.3). ONE isolated change:
// k_mega GEMM path de-capped. Round-17 showed launch_bounds min-waves made
// the compiler squeeze to 36 VGPR -> ~4 loads in flight/wave -> 0.5 MB
// in-flight chip-wide -> latency-bound at ~1 TB/s. Now: no min-waves bound,
// and all 16 x-loads of the strip are hoisted explicitly before the MFMA
// chain (16 concurrent 32B loads/wave).
// 4 dispatches. I/O: fp32 in, int32 idx, fp32 out.

#define NNODES 50000
#define NEDGES 800000
#define IN_F   256
#define HID    128
#define OUTF   64

#define PA_EPT   8
#define PA_EDGES (256 * PA_EPT)                          // 2048 edges/block
#define PA_NB    ((NEDGES + PA_EDGES - 1) / PA_EDGES)    // 391 blocks
#define NBKT     ((NNODES + 255) / 256)                  // 196 buckets (dst>>8)
#define BCAP     5120                                    // bucket capacity (lam=4082)
#define NSTRIP   (NNODES / 16)                           // 3125 strips
#define GB       ((NSTRIP + 3) / 4)                      // 782 gemm blocks

typedef unsigned short u16;
typedef unsigned long long u64;
typedef __bf16 bf16x8 __attribute__((ext_vector_type(8)));
typedef float  f32x4  __attribute__((ext_vector_type(4)));

__device__ __forceinline__ u16 f2b(float f) {
    union { float f; unsigned u; } v; v.f = f;
    unsigned u = v.u;
    return (u16)((u + 0x7fffu + ((u >> 16) & 1u)) >> 16);  // RNE fp32->bf16
}
__device__ __forceinline__ float b2f_lo(unsigned v) {
    union { unsigned u; float f; } c; c.u = (v & 0xffffu) << 16; return c.f;
}
__device__ __forceinline__ float b2f_hi(unsigned v) {
    union { unsigned u; float f; } c; c.u = v & 0xffff0000u; return c.f;
}
__device__ __forceinline__ float lrelu02_exp(float t) {
    t = t > 0.f ? t : 0.2f * t;                        // leaky_relu(0.2)
    return __expf(t);
}

// ---------------------------------------------------------------------------
// pack0: blocks 0..15 pack W_gat, 16..19 pack W_lin, 20 zeroes bcnt.
__global__ __launch_bounds__(256) void pack0(const float* __restrict__ Wg,
                                             const float* __restrict__ Wl,
                                             u16* __restrict__ pWg,
                                             u16* __restrict__ pWl,
                                             int* __restrict__ bcnt) {
    int blk = blockIdx.x, tid = threadIdx.x;
    if (blk < 16) {
        int t = blk * 256 + tid;
        int lane = t & 63, tile = t >> 6;
        int nt = tile & 7, kt = tile >> 3;
        int col = lane & 15, quad = lane >> 4;
        int krow = kt * 32 + quad * 8;
        int ncol = nt * 16 + col;
#pragma unroll
        for (int j = 0; j < 8; j++) pWg[t * 8 + j] = f2b(Wg[(krow + j) * HID + ncol]);
    } else if (blk < 20) {
        int t = (blk - 16) * 256 + tid;
        int lane = t & 63, tile = t >> 6;
        int nt = tile & 3, kt = tile >> 2;
        int col = lane & 15, quad = lane >> 4;
        int o  = nt * 16 + col;
        int k0 = kt * 32 + quad * 8;
#pragma unroll
        for (int j = 0; j < 8; j++) pWl[t * 8 + j] = f2b(Wl[o * HID + k0 + j]);
    } else {
        if (tid < NBKT) bcnt[tid] = 0;
    }
}

// ---------------------------------------------------------------------------
// k_mega: blocks [0,GB) = feat GEMM (1 strip/wave, 16 hoisted x-loads,
// fused el/er epilogue); blocks [GB, GB+PA_NB) = edge partition into 196
// bucket regions. The two paths are data-independent and run concurrently.
__global__ __launch_bounds__(256) void k_mega(
        const float* __restrict__ x, const u16* __restrict__ pWg,
        const float* __restrict__ al_, const float* __restrict__ ar_,
        unsigned* __restrict__ feat2, float* __restrict__ el, float* __restrict__ er,
        const int* __restrict__ src, const int* __restrict__ dst,
        int* __restrict__ bcnt, u64* __restrict__ pairs) {
    __shared__ u64 smemU[21504 / 8];
    char* smem = (char*)smemU;
    int blk = blockIdx.x, tid = threadIdx.x;

    if (blk < GB) {
        // ---- feat GEMM path (no LDS use) ----
        int wave = tid >> 6, lane = tid & 63;
        int strip = blk * 4 + wave;
        if (strip >= NSTRIP) return;
        int m0 = strip * 16;
        int col = lane & 15, quad = lane >> 4;

        // hoist ALL x loads for this strip: 16 independent 16B loads/lane
        f32x4 xa[16];
        const float* xr = x + (size_t)(m0 + col) * IN_F + quad * 8;
#pragma unroll
        for (int kt = 0; kt < 8; kt++) {
            xa[2 * kt]     = *reinterpret_cast<const f32x4*>(xr + kt * 32);
            xa[2 * kt + 1] = *reinterpret_cast<const f32x4*>(xr + kt * 32 + 4);
        }
        bf16x8 av[8];
#pragma unroll
        for (int kt = 0; kt < 8; kt++)
#pragma unroll
            for (int j = 0; j < 4; j++) {
                av[kt][j]     = (__bf16)xa[2 * kt][j];
                av[kt][4 + j] = (__bf16)xa[2 * kt + 1][j];
            }

        f32x4 acc[8] = {};
#pragma unroll
        for (int kt = 0; kt < 8; kt++)
#pragma unroll
            for (int nt = 0; nt < 8; nt++) {
                bf16x8 b = *reinterpret_cast<const bf16x8*>(pWg + ((kt * 8 + nt) * 64 + lane) * 8);
                acc[nt] = __builtin_amdgcn_mfma_f32_16x16x32_bf16(av[kt], b, acc[nt], 0, 0, 0);
            }

        // epilogue: el/er dot products + bf16 feat store
        float pl[4] = {0, 0, 0, 0}, pr[4] = {0, 0, 0, 0};
#pragma unroll
        for (int nt = 0; nt < 8; nt++) {
            float alv = al_[nt * 16 + col], arv = ar_[nt * 16 + col];
#pragma unroll
            for (int reg = 0; reg < 4; reg++) {
                pl[reg] += acc[nt][reg] * alv;
                pr[reg] += acc[nt][reg] * arv;
            }
        }
#pragma unroll
        for (int m = 1; m < 16; m <<= 1)
#pragma unroll
            for (int reg = 0; reg < 4; reg++) {
                pl[reg] += __shfl_xor(pl[reg], m, 64);
                pr[reg] += __shfl_xor(pr[reg], m, 64);
            }
        if (col == 0) {
#pragma unroll
            for (int reg = 0; reg < 4; reg++) {
                el[m0 + quad * 4 + reg] = pl[reg];
                er[m0 + quad * 4 + reg] = pr[reg];
            }
        }
#pragma unroll
        for (int nt = 0; nt < 8; nt++)
#pragma unroll
            for (int reg = 0; reg < 4; reg++) {
                u16* fp = (u16*)feat2;
                fp[(size_t)(m0 + quad * 4 + reg) * HID + nt * 16 + col] = f2b(acc[nt][reg]);
            }
        return;
    }

    // ---- edge partition path ----
    int* hist    = (int*)smem;                         // 256 ints (196 used)
    int* binbase = hist + 256;
    int* gbase   = binbase + 256;
    int* fill    = gbase + 256;
    int* stmp    = fill + 256;                         // 256 ints -> 5120 B
    u64* spair   = (u64*)(smem + 5120);                // 2048 * 8 = 16384 B

    int e0 = (blk - GB) * PA_EDGES;
    int cnt = NEDGES - e0; if (cnt > PA_EDGES) cnt = PA_EDGES;

    hist[tid] = 0; fill[tid] = 0;
    __syncthreads();

    int es[PA_EPT], ed[PA_EPT];
#pragma unroll
    for (int j = 0; j < PA_EPT; j++) {
        int idx = e0 + j * 256 + tid;
        if (idx < NEDGES) {
            es[j] = src[idx];
            ed[j] = dst[idx];
            atomicAdd(&hist[ed[j] >> 8], 1);
        } else ed[j] = -1;
    }
    __syncthreads();

    stmp[tid] = (tid < NBKT) ? hist[tid] : 0;
    __syncthreads();
#pragma unroll
    for (int ofs = 1; ofs < 256; ofs <<= 1) {
        int u = (tid >= ofs) ? stmp[tid - ofs] : 0;
        __syncthreads();
        stmp[tid] += u;
        __syncthreads();
    }
    if (tid < NBKT) {
        binbase[tid] = stmp[tid] - hist[tid];
        if (hist[tid] > 0)
            gbase[tid] = tid * BCAP + atomicAdd(&bcnt[tid], hist[tid]);
    }
    __syncthreads();

#pragma unroll
    for (int j = 0; j < PA_EPT; j++) {
        if (ed[j] >= 0) {
            int b = ed[j] >> 8;
            int r = atomicAdd(&fill[b], 1);
            int loc = binbase[b] + r;
            spair[loc] = ((u64)(unsigned)ed[j] << 32) | (unsigned)es[j];
        }
    }
    __syncthreads();

    for (int i = tid; i < cnt; i += 256) {
        u64 p = spair[i];
        int b = (int)(p >> 40);                        // dst>>8 from packed pair
        pairs[gbase[b] + (i - binbase[b])] = p;
    }
}

// ---------------------------------------------------------------------------
// k_fine: one block (512 thr) per bucket (196 buckets x 256 nodes). Builds
// per-node CSR in LDS, computes ew (1 thread/edge) + den, scatters into the
// bucket's contiguous window.
__global__ __launch_bounds__(512) void k_fine(const u64* __restrict__ pairs,
                                              const int* __restrict__ bcnt,
                                              const float* __restrict__ el,
                                              const float* __restrict__ er,
                                              int* __restrict__ rowptr,
                                              int* __restrict__ esrc,
                                              float* __restrict__ ew,
                                              float* __restrict__ den) {
    __shared__ int sbc[256];
    __shared__ int nh[256];
    __shared__ int wsum[256];
    __shared__ int cur[256];
    __shared__ float dls[256];
    __shared__ float erl[256];

    int b = blockIdx.x, tid = threadIdx.x;
    int nb = b << 8;
    int nn = NNODES - nb; if (nn > 256) nn = 256;

    if (tid < 256) sbc[tid] = (tid < NBKT) ? bcnt[tid] : 0;
    __syncthreads();
#pragma unroll
    for (int ofs = 1; ofs < 256; ofs <<= 1) {
        int u = 0;
        if (tid < 256 && tid >= ofs) u = sbc[tid - ofs];
        __syncthreads();
        if (tid < 256) sbc[tid] += u;
        __syncthreads();
    }
    int cntb = bcnt[b];
    int base = sbc[b] - cntb;                          // exclusive prefix
    const u64* reg = pairs + (size_t)b * BCAP;

    if (tid < 256) {
        nh[tid] = 0;
        dls[tid] = 0.f;
        erl[tid] = (tid < nn) ? er[nb + tid] : 0.f;
    }
    __syncthreads();
    for (int i = tid; i < cntb; i += 512) {
        int d = (int)(unsigned)(reg[i] >> 32);
        atomicAdd(&nh[d - nb], 1);
    }
    __syncthreads();

    int c = (tid < 256) ? nh[tid] : 0;
    if (tid < 256) wsum[tid] = c;
    __syncthreads();
#pragma unroll
    for (int ofs = 1; ofs < 256; ofs <<= 1) {
        int u = 0;
        if (tid < 256 && tid >= ofs) u = wsum[tid - ofs];
        __syncthreads();
        if (tid < 256) wsum[tid] += u;
        __syncthreads();
    }
    if (tid < 256) {
        int o = base + wsum[tid] - c;
        cur[tid] = o;
        if (tid < nn) rowptr[nb + tid] = o;
    }
    if (b == NBKT - 1 && tid == 0) rowptr[NNODES] = NEDGES;
    __syncthreads();

    for (int i = tid; i < cntb; i += 512) {
        u64 p = reg[i];
        int s_ = (int)(unsigned)(p & 0xffffffffu);
        int d  = (int)(unsigned)(p >> 32);
        int dl = d - nb;
        float w = lrelu02_exp(el[s_] + erl[dl]);
        int pos = atomicAdd(&cur[dl], 1);
        esrc[pos] = s_;
        ew[pos] = w;
        atomicAdd(&dls[dl], w);
    }
    __syncthreads();
    if (tid < nn) den[nb + tid] = dls[tid];
}

// ---------------------------------------------------------------------------
// Fused aggregation + output GEMM, 8-way-unrolled gather loop.
__global__ __launch_bounds__(256) void k_aggout(const int* __restrict__ rowptr,
                                                const int* __restrict__ esrc,
                                                const float* __restrict__ ew,
                                                const float* __restrict__ den,
                                                const unsigned* __restrict__ feat2,
                                                const float* __restrict__ bias,
                                                const u16* __restrict__ pWl,
                                                float* __restrict__ out) {
    __shared__ unsigned sg[16 * 68];
    int wave = threadIdx.x >> 6, lane = threadIdx.x & 63;
    int m0 = blockIdx.x * 16;
    float bl = bias[lane * 2 + 0], bh = bias[lane * 2 + 1];

    for (int i = 0; i < 4; i++) {
        int r = wave * 4 + i;
        int n = m0 + r;
        int beg = rowptr[n], end = rowptr[n + 1];

        float p0 = 0.f, p1 = 0.f, q0 = 0.f, q1 = 0.f;
        float r0 = 0.f, r1 = 0.f, t0 = 0.f, t1 = 0.f;
        float u0 = 0.f, u1 = 0.f, x0 = 0.f, x1 = 0.f;
        float y0 = 0.f, y1 = 0.f, z0 = 0.f, z1 = 0.f;
        int j = beg;
        for (; j + 8 <= end; j += 8) {
            int s0 = esrc[j],     s1 = esrc[j + 1], s2 = esrc[j + 2], s3 = esrc[j + 3];
            int s4 = esrc[j + 4], s5 = esrc[j + 5], s6 = esrc[j + 6], s7 = esrc[j + 7];
            unsigned v0 = feat2[(size_t)s0 * 64 + lane];
            unsigned v1 = feat2[(size_t)s1 * 64 + lane];
            unsigned v2 = feat2[(size_t)s2 * 64 + lane];
            unsigned v3 = feat2[(size_t)s3 * 64 + lane];
            unsigned v4 = feat2[(size_t)s4 * 64 + lane];
            unsigned v5 = feat2[(size_t)s5 * 64 + lane];
            unsigned v6 = feat2[(size_t)s6 * 64 + lane];
            unsigned v7 = feat2[(size_t)s7 * 64 + lane];
            float w0 = ew[j],     w1 = ew[j + 1], w2 = ew[j + 2], w3 = ew[j + 3];
            float w4 = ew[j + 4], w5 = ew[j + 5], w6 = ew[j + 6], w7 = ew[j + 7];
            p0 += w0 * b2f_lo(v0); p1 += w0 * b2f_hi(v0);
            q0 += w1 * b2f_lo(v1); q1 += w1 * b2f_hi(v1);
            r0 += w2 * b2f_lo(v2); r1 += w2 * b2f_hi(v2);
            t0 += w3 * b2f_lo(v3); t1 += w3 * b2f_hi(v3);
            u0 += w4 * b2f_lo(v4); u1 += w4 * b2f_hi(v4);
            x0 += w5 * b2f_lo(v5); x1 += w5 * b2f_hi(v5);
            y0 += w6 * b2f_lo(v6); y1 += w6 * b2f_hi(v6);
            z0 += w7 * b2f_lo(v7); z1 += w7 * b2f_hi(v7);
        }
        if (j + 4 <= end) {
            int s0 = esrc[j], s1 = esrc[j + 1], s2 = esrc[j + 2], s3 = esrc[j + 3];
            unsigned v0 = feat2[(size_t)s0 * 64 + lane];
            unsigned v1 = feat2[(size_t)s1 * 64 + lane];
            unsigned v2 = feat2[(size_t)s2 * 64 + lane];
            unsigned v3 = feat2[(size_t)s3 * 64 + lane];
            float w0 = ew[j], w1 = ew[j + 1], w2 = ew[j + 2], w3 = ew[j + 3];
            p0 += w0 * b2f_lo(v0); p1 += w0 * b2f_hi(v0);
            q0 += w1 * b2f_lo(v1); q1 += w1 * b2f_hi(v1);
            r0 += w2 * b2f_lo(v2); r1 += w2 * b2f_hi(v2);
            t0 += w3 * b2f_lo(v3); t1 += w3 * b2f_hi(v3);
            j += 4;
        }
        for (; j < end; j++) {
            int s = esrc[j];
            float w = ew[j];
            unsigned v = feat2[(size_t)s * 64 + lane];
            p0 += w * b2f_lo(v); p1 += w * b2f_hi(v);
        }
        float a0 = ((p0 + q0) + (r0 + t0)) + ((u0 + x0) + (y0 + z0));
        float a1 = ((p1 + q1) + (r1 + t1)) + ((u1 + x1) + (y1 + z1));

        float dn = den[n];
        float inv = dn > 0.f ? 1.f / dn : 0.f;         // isolated node -> 0
        float g0 = a0 * inv + bl;
        float g1 = a1 * inv + bh;
        g0 = g0 > 0.f ? g0 : 0.01f * g0;               // leaky_relu(0.01)
        g1 = g1 > 0.f ? g1 : 0.01f * g1;
        sg[r * 68 + lane] = (unsigned)f2b(g0) | ((unsigned)f2b(g1) << 16);
    }
    __syncthreads();

    int col = lane & 15, quad = lane >> 4;
    int nt = wave;
    f32x4 acc = {};
#pragma unroll
    for (int kt = 0; kt < 4; kt++) {
        bf16x8 a = *reinterpret_cast<const bf16x8*>(&sg[col * 68 + kt * 16 + quad * 4]);
        bf16x8 bf = *reinterpret_cast<const bf16x8*>(pWl + ((kt * 4 + nt) * 64 + lane) * 8);
        acc = __builtin_amdgcn_mfma_f32_16x16x32_bf16(a, bf, acc, 0, 0, 0);
    }
#pragma unroll
    for (int reg = 0; reg < 4; reg++)
        out[(size_t)(m0 + quad * 4 + reg) * OUTF + nt * 16 + col] = acc[reg];
}

// ---------------------------------------------------------------------------
extern "C" void kernel_launch(void* const* d_in, const int* in_sizes, int n_in,
                              void* d_out, int out_size, void* d_ws, size_t ws_size,
                              hipStream_t stream) {
    const float* x      = (const float*)d_in[0];   // [50000,256] fp32
    const int*   src    = (const int*)d_in[1];     // [800000] int32
    const int*   dst    = (const int*)d_in[2];     // [800000] int32
    const float* Wg     = (const float*)d_in[3];   // [256,128] fp32
    const float* attn_l = (const float*)d_in[4];   // [128]
    const float* attn_r = (const float*)d_in[5];   // [128]
    const float* bias   = (const float*)d_in[6];   // [128]
    const float* Wl     = (const float*)d_in[7];   // [64,128] fp32
    float* out          = (float*)d_out;           // [50000,64] fp32

    char* ws = (char*)d_ws;
    size_t off = 0;
    auto alloc = [&](size_t b) { size_t r = off; off += (b + 255) & ~(size_t)255; return r; };
    size_t pwgOff  = alloc((size_t)8 * 8 * 64 * 8 * 2);     // 64 KB
    size_t pwlOff  = alloc((size_t)4 * 4 * 64 * 8 * 2);     // 16 KB
    size_t featOff = alloc((size_t)NNODES * HID * 2);       // 12.8 MB bf16 feat
    size_t elOff   = alloc((size_t)NNODES * 4);
    size_t erOff   = alloc((size_t)NNODES * 4);
    size_t denOff  = alloc((size_t)NNODES * 4);
    size_t rowOff  = alloc((size_t)(NNODES + 1) * 4);
    size_t esrcOff = alloc((size_t)NEDGES * 4);
    size_t ewOff   = alloc((size_t)NEDGES * 4);
    size_t pairOff = alloc((size_t)NBKT * BCAP * 8);        // 8.0 MB bucket regions
    size_t bcntOff = alloc((size_t)NBKT * 4);

    u16*      pWg   = (u16*)(ws + pwgOff);
    u16*      pWl   = (u16*)(ws + pwlOff);
    unsigned* feat2 = (unsigned*)(ws + featOff);
    float*    el    = (float*)(ws + elOff);
    float*    er    = (float*)(ws + erOff);
    float*    den   = (float*)(ws + denOff);
    int*      rowp  = (int*)(ws + rowOff);
    int*      esrc  = (int*)(ws + esrcOff);
    float*    ew    = (float*)(ws + ewOff);
    u64*      pairs = (u64*)(ws + pairOff);
    int*      bcnt  = (int*)(ws + bcntOff);

    pack0<<<21, 256, 0, stream>>>(Wg, Wl, pWg, pWl, bcnt);
    k_mega<<<GB + PA_NB, 256, 0, stream>>>(x, pWg, attn_l, attn_r, feat2, el, er,
                                           src, dst, bcnt, pairs);
    k_fine<<<NBKT, 512, 0, stream>>>(pairs, bcnt, el, er, rowp, esrc, ew, den);
    k_aggout<<<NNODES / 16, 256, 0, stream>>>(rowp, esrc, ew, den, feat2, bias,
                                              pWl, out);
}